// Round 6
// baseline (230.553 us; speedup 1.0000x reference)
//
#include <hip/hip_runtime.h>

#define KCAP 96u
#define CAP 6144          // cached pos-cell list capacity
#define PBLK 512          // pair_kernel block size
#define NTOT 344064       // 16*(16384+4096+1024)
#define NPAIR 1536
#define NOBJB 1344

__device__ __forceinline__ float softplus_f(float x) {
    return fmaxf(x, 0.0f) + log1pf(expf(-fabsf(x)));
}

// Exact reproduction of the reference geometry (no fma contraction so we
// match XLA's elementwise fp32 at the selection decision boundaries).
__device__ __forceinline__ void tri_pos_dist(
    float px, float py,
    float ax, float ay, float bx, float by, float cx, float cy,
    bool& pos, float& dist)
{
#pragma clang fp contract(off)
    float d1 = (px - bx) * (ay - by) - (ax - bx) * (py - by);
    float d2 = (px - cx) * (by - cy) - (bx - cx) * (py - cy);
    float d3 = (px - ax) * (cy - ay) - (cx - ax) * (py - ay);
    bool has_neg = (d1 < 0.f) | (d2 < 0.f) | (d3 < 0.f);
    bool has_pos = (d1 > 0.f) | (d2 > 0.f) | (d3 > 0.f);
    bool inside = !(has_neg && has_pos);

    float dAB, dBC, dCA;
    {
        float vx = bx - ax, vy = by - ay, wx = px - ax, wy = py - ay;
        float t = (wx*vx + wy*vy) / (vx*vx + vy*vy + 1e-9f);
        t = fminf(fmaxf(t, 0.0f), 1.0f);
        float dx = px - (ax + t*vx), dy = py - (ay + t*vy);
        dAB = sqrtf(dx*dx + dy*dy + 1e-12f);
    }
    {
        float vx = cx - bx, vy = cy - by, wx = px - bx, wy = py - by;
        float t = (wx*vx + wy*vy) / (vx*vx + vy*vy + 1e-9f);
        t = fminf(fmaxf(t, 0.0f), 1.0f);
        float dx = px - (bx + t*vx), dy = py - (by + t*vy);
        dBC = sqrtf(dx*dx + dy*dy + 1e-12f);
    }
    {
        float vx = ax - cx, vy = ay - cy, wx = px - cx, wy = py - cy;
        float t = (wx*vx + wy*vy) / (vx*vx + vy*vy + 1e-9f);
        t = fminf(fmaxf(t, 0.0f), 1.0f);
        float dx = px - (cx + t*vx), dy = py - (cy + t*vy);
        dCA = sqrtf(dx*dx + dy*dy + 1e-12f);
    }
    dist = fminf(dAB, fminf(dBC, dCA));
    pos = inside || (dist <= 3.0f);
}

__global__ void zero_kernel(unsigned* __restrict__ p, int n) {
    int i = blockIdx.x * 256 + threadIdx.x;
    if (i < n) p[i] = 0u;
}

// One block (512 threads) per (level, b, g) pair. Pass A: one heavy pass over
// the ETA-expanded bbox, histogramming the top-11 bits of the fp32 dist
// pattern AND caching (bits, hw) of pos cells in LDS. If the cache holds all
// pos cells, the exact 32-bit kth is refined from the cache with two cheap
// LDS passes. If >CAP: one MORE heavy pass re-caches only cells with
// bin <= T (bounded by 96 + bin-T count), then the same LDS refinement runs.
// Ultra-rare double-overflow falls back to heavy radix passes. Ties are
// full-bit-equal, ranked by hw (matches jax.lax.top_k).
__global__ __launch_bounds__(PBLK) void pair_kernel(
    const float* __restrict__ gt,
    const float* __restrict__ reg0, const float* __restrict__ cls0,
    const float* __restrict__ reg1, const float* __restrict__ cls1,
    const float* __restrict__ reg2, const float* __restrict__ cls2,
    unsigned* __restrict__ objbits,
    double* __restrict__ pair_reg, double* __restrict__ pair_cls,
    unsigned* __restrict__ pair_pos)
{
    const int bid = blockIdx.x;
    const int level = bid >> 9;        // 512 pairs per level
    const int pair = bid & 511;
    const int b = pair >> 5;

    int W, HW, shift, objbase;
    float stride;
    const float* pr; const float* pcl;
    if (level == 0)      { W = 128; HW = 16384; shift = 7; stride = 8.0f;  objbase = 0;     pr = reg0; pcl = cls0; }
    else if (level == 1) { W = 64;  HW = 4096;  shift = 6; stride = 16.0f; objbase = 8192;  pr = reg1; pcl = cls1; }
    else                 { W = 32;  HW = 1024;  shift = 5; stride = 32.0f; objbase = 10240; pr = reg2; pcl = cls2; }
    const int wmask = W - 1;

    const float* gp = gt + pair * 6;
    const float ax = gp[0], ay = gp[1];
    const float bx = gp[2], by = gp[3];
    const float cx = gp[4], cy = gp[5];

    // ---- expanded bbox of candidate cells (conservative, +1 cell margin) ----
    const float inv = 1.0f / stride;   // power of two: exact
    float minx = fminf(ax, fminf(bx, cx)), maxx = fmaxf(ax, fmaxf(bx, cx));
    float miny = fminf(ay, fminf(by, cy)), maxy = fmaxf(ay, fmaxf(by, cy));
    int wlo = max(0,     (int)floorf((minx - 3.0f) * inv - 0.5f) - 1);
    int whi = min(W - 1, (int)ceilf ((maxx + 3.0f) * inv - 0.5f) + 1);
    int hlo = max(0,     (int)floorf((miny - 3.0f) * inv - 0.5f) - 1);
    int hhi = min(W - 1, (int)ceilf ((maxy + 3.0f) * inv - 0.5f) + 1);
    const int ncols = max(0, whi - wlo + 1);
    const int nb = (hhi - hlo + 1 > 0) ? (hhi - hlo + 1) * ncols : 0;
    const int nbR = (nb + PBLK - 1) & ~(PBLK - 1);

    __shared__ unsigned hist[2048];
    __shared__ unsigned chunk[256];
    __shared__ unsigned chunk4[64];
    __shared__ unsigned s_bits[CAP];
    __shared__ unsigned short s_hw[CAP];
    __shared__ unsigned s_cnt, s_T, s_k, s_tiecnt;
    __shared__ double red_reg[8], red_cls[8];
    __shared__ unsigned red_pos[8];
    unsigned* tie_hw = hist;   // alias: hist is dead once ties are collected

    const int tid = threadIdx.x;
    const int lane = tid & 63;
    if (tid == 0) { s_cnt = 0u; s_tiecnt = 0u; }
    for (int j = tid; j < 2048; j += PBLK) hist[j] = 0u;
    __syncthreads();

    // two-level kth scan: hist -> chunk(256x8) -> chunk4(64x32); out: s_T, s_k
    auto kth_scan = [&](unsigned kk) {
        __syncthreads();
        if (tid < 256) {
            unsigned s = 0; int base = tid * 8;
            #pragma unroll
            for (int j = 0; j < 8; ++j) s += hist[base + j];
            chunk[tid] = s;
        }
        __syncthreads();
        if (tid < 64) {
            int b4 = tid * 4;
            chunk4[tid] = chunk[b4] + chunk[b4+1] + chunk[b4+2] + chunk[b4+3];
        }
        __syncthreads();
        if (tid == 0) {
            unsigned cum = 0; int t4 = 0;
            while (cum + chunk4[t4] < kk) { cum += chunk4[t4]; ++t4; }
            int t = t4 * 4;
            while (cum + chunk[t] < kk) { cum += chunk[t]; ++t; }
            int bb = t * 8;
            while (cum + hist[bb] < kk) { cum += hist[bb]; ++bb; }
            s_T = (unsigned)bb;
            s_k = kk - cum;
        }
        __syncthreads();
    };

    // ---- pass A: single heavy pass; histogram top-11 bits + cache pos cells ----
    for (int i = tid; i < nbR; i += PBLK) {
        bool pos = false; unsigned bits = 0u; int hw = 0;
        if (i < nb) {
            int q = i / ncols;
            int w = wlo + (i - q * ncols);
            int h = hlo + q;
            hw = (h << shift) | w;
            float px = (w + 0.5f) * stride;
            float py = (h + 0.5f) * stride;
            float dist;
            tri_pos_dist(px, py, ax, ay, bx, by, cx, cy, pos, dist);
            if (pos) { bits = __float_as_uint(dist); atomicAdd(&hist[bits >> 21], 1u); }
        }
        unsigned long long m = __ballot(pos);
        if (m) {
            int leader = __ffsll(m) - 1;
            unsigned base = 0u;
            if (lane == leader) base = atomicAdd(&s_cnt, (unsigned)__popcll(m));
            base = __shfl(base, leader);
            if (pos) {
                unsigned slot = base + (unsigned)__popcll(m & ((1ull << lane) - 1ull));
                if (slot < CAP) { s_bits[slot] = bits; s_hw[slot] = (unsigned short)hw; }
            }
        }
    }
    __syncthreads();

    const unsigned total = s_cnt;
    const bool fullsel = (total <= KCAP);
    unsigned n = min(total, (unsigned)CAP);
    unsigned kth_bits = 0u, tie_need = 0u;
    bool radix_fb = false;

    if (!fullsel) {
        kth_scan(KCAP);                  // T bin of kth + within-bin rank
        const unsigned T = s_T, kk1 = s_k;

        if (total > CAP) {
            // ---- hybrid: heavy pass 2 re-caches only cells with bin <= T ----
            if (tid == 0) s_cnt = 0u;
            __syncthreads();
            for (int i = tid; i < nbR; i += PBLK) {
                bool keep = false; unsigned bits = 0u; int hw = 0;
                if (i < nb) {
                    int q = i / ncols;
                    int w = wlo + (i - q * ncols);
                    int h = hlo + q;
                    hw = (h << shift) | w;
                    float px = (w + 0.5f) * stride;
                    float py = (h + 0.5f) * stride;
                    bool pos; float dist;
                    tri_pos_dist(px, py, ax, ay, bx, by, cx, cy, pos, dist);
                    if (pos) {
                        bits = __float_as_uint(dist);
                        keep = ((bits >> 21) <= T);
                    }
                }
                unsigned long long m = __ballot(keep);
                if (m) {
                    int leader = __ffsll(m) - 1;
                    unsigned base = 0u;
                    if (lane == leader) base = atomicAdd(&s_cnt, (unsigned)__popcll(m));
                    base = __shfl(base, leader);
                    if (keep) {
                        unsigned slot = base + (unsigned)__popcll(m & ((1ull << lane) - 1ull));
                        if (slot < CAP) { s_bits[slot] = bits; s_hw[slot] = (unsigned short)hw; }
                    }
                }
            }
            __syncthreads();
            n = s_cnt;
            if (n > CAP) { radix_fb = true; }
        }

        if (!radix_fb) {
            // ---- exact kth via 2 cheap LDS refinement passes over cache ----
            __syncthreads();
            for (int j = tid; j < 2048; j += PBLK) hist[j] = 0u;
            __syncthreads();
            for (unsigned i = tid; i < n; i += PBLK) {
                unsigned bi = s_bits[i];
                if ((bi >> 21) == T) atomicAdd(&hist[(bi >> 10) & 0x7FFu], 1u);
            }
            kth_scan(kk1);
            unsigned prefix = (T << 11) | s_T;   // top 22 bits
            unsigned kk2 = s_k;
            __syncthreads();
            for (int j = tid; j < 2048; j += PBLK) hist[j] = 0u;
            __syncthreads();
            for (unsigned i = tid; i < n; i += PBLK) {
                unsigned bi = s_bits[i];
                if ((bi >> 10) == prefix) atomicAdd(&hist[bi & 0x3FFu], 1u);
            }
            kth_scan(kk2);
            kth_bits = (prefix << 10) | s_T;     // full 32-bit kth pattern
            tie_need = s_k;
        }
    }

    // ---- contribution ----
    double regAcc = 0.0, clsAcc = 0.0;
    unsigned posAcc = 0u;

    auto contribute = [&](int hw) {
        int h = hw >> shift, w = hw & wmask;
        float px = (w + 0.5f) * stride;
        float py = (h + 0.5f) * stride;
        const float* base = pr + (size_t)b * 6 * HW + hw;
        float p0x = base[0],          p0y = base[HW];
        float p1x = base[2 * HW],     p1y = base[3 * HW];
        float p2x = base[4 * HW],     p2y = base[5 * HW];
        float g0x = (ax - px) * inv,  g0y = (ay - py) * inv;
        float g1x = (bx - px) * inv,  g1y = (by - py) * inv;
        float g2x = (cx - px) * inv,  g2y = (cy - py) * inv;
        float dx0 = p0x - g0x, dy0 = p0y - g0y;
        float p0t = dx0 * dx0 + dy0 * dy0;
        float e11x = p1x - g1x, e11y = p1y - g1y;
        float e12x = p1x - g2x, e12y = p1y - g2y;
        float e21x = p2x - g1x, e21y = p2y - g1y;
        float e22x = p2x - g2x, e22y = p2y - g2y;
        float d11 = sqrtf(e11x * e11x + e11y * e11y);
        float d12 = sqrtf(e12x * e12x + e12y * e12y);
        float d21 = sqrtf(e21x * e21x + e21y * e21y);
        float d22 = sqrtf(e22x * e22x + e22y * e22y);
        float cd = fminf(d11, d12) + fminf(d21, d22) + fminf(d11, d21) + fminf(d12, d22);
        regAcc += (double)(p0t + cd);
        clsAcc += (double)softplus_f(-pcl[(size_t)b * HW + hw]);
        posAcc += 1u;
        unsigned bi = (unsigned)(b * HW + hw);
        atomicOr(&objbits[objbase + (bi >> 5)], 1u << (bi & 31u));
    };

    if (fullsel) {
        for (unsigned i = tid; i < n; i += PBLK) contribute((int)s_hw[i]);
    } else if (!radix_fb) {
        for (unsigned i = tid; i < n; i += PBLK) {
            unsigned bi = s_bits[i];
            if (bi < kth_bits) {
                contribute((int)s_hw[i]);
            } else if (bi == kth_bits) {
                unsigned t = atomicAdd(&s_tiecnt, 1u);
                if (t < 2048u) tie_hw[t] = s_hw[i];
            }
        }
        __syncthreads();
        unsigned tn = min(s_tiecnt, 2048u);
        for (unsigned i = tid; i < tn; i += PBLK) {
            unsigned hwv = tie_hw[i], rank = 0;
            for (unsigned j = 0; j < tn; ++j) rank += (tie_hw[j] < hwv) ? 1u : 0u;
            if (rank < tie_need) contribute((int)hwv);
        }
    } else {
        // ---- ultra-rare fallback: heavy radix p=1,2 + final heavy pass ----
        unsigned prefix = s_T;   // still T from kth_scan(KCAP): s_T/s_k untouched
        for (int p = 1; p < 3; ++p) {
            unsigned kk = s_k;
            __syncthreads();
            for (int j = tid; j < 2048; j += PBLK) hist[j] = 0u;
            __syncthreads();
            for (int i = tid; i < nb; i += PBLK) {
                int q = i / ncols;
                int w = wlo + (i - q * ncols);
                int h = hlo + q;
                float px = (w + 0.5f) * stride;
                float py = (h + 0.5f) * stride;
                bool pos; float dist;
                tri_pos_dist(px, py, ax, ay, bx, by, cx, cy, pos, dist);
                if (!pos) continue;
                unsigned bits = __float_as_uint(dist);
                unsigned bin;
                if (p == 1) { if ((bits >> 21) != prefix) continue; bin = (bits >> 10) & 0x7FFu; }
                else        { if ((bits >> 10) != prefix) continue; bin = bits & 0x3FFu; }
                atomicAdd(&hist[bin], 1u);
            }
            kth_scan(kk);
            prefix = (p == 1) ? ((prefix << 11) | s_T) : ((prefix << 10) | s_T);
        }
        const unsigned kth = prefix, need = s_k;
        for (int i = tid; i < nb; i += PBLK) {
            int q = i / ncols;
            int w = wlo + (i - q * ncols);
            int h = hlo + q;
            int hw = (h << shift) | w;
            float px = (w + 0.5f) * stride;
            float py = (h + 0.5f) * stride;
            bool pos; float dist;
            tri_pos_dist(px, py, ax, ay, bx, by, cx, cy, pos, dist);
            if (!pos) continue;
            unsigned bits = __float_as_uint(dist);
            if (bits < kth) {
                contribute(hw);
            } else if (bits == kth) {
                unsigned t = atomicAdd(&s_tiecnt, 1u);
                if (t < 2048u) tie_hw[t] = (unsigned)hw;
            }
        }
        __syncthreads();
        unsigned tn = min(s_tiecnt, 2048u);
        for (unsigned i = tid; i < tn; i += PBLK) {
            unsigned hwv = tie_hw[i], rank = 0;
            for (unsigned j = 0; j < tn; ++j) rank += (tie_hw[j] < hwv) ? 1u : 0u;
            if (rank < need) contribute((int)hwv);
        }
    }

    // ---- block reduce + per-block partial write ----
    for (int off = 32; off > 0; off >>= 1) {
        regAcc += __shfl_down(regAcc, off);
        clsAcc += __shfl_down(clsAcc, off);
        posAcc += __shfl_down(posAcc, off);
    }
    int wave = tid >> 6;
    if (lane == 0) { red_reg[wave] = regAcc; red_cls[wave] = clsAcc; red_pos[wave] = posAcc; }
    __syncthreads();
    if (tid == 0) {
        double rs = 0.0, cs = 0.0; unsigned ps = 0u;
        #pragma unroll
        for (int i = 0; i < 8; ++i) { rs += red_reg[i]; cs += red_cls[i]; ps += red_pos[i]; }
        pair_reg[bid] = rs;
        pair_cls[bid] = cs;
        pair_pos[bid] = ps;
    }
}

// obj BCE partials + last-block final reduction (ticket pattern).
__global__ __launch_bounds__(256) void objfin_kernel(
    const float* __restrict__ o0, const float* __restrict__ o1, const float* __restrict__ o2,
    const unsigned* __restrict__ objbits,
    const double* __restrict__ pair_reg, const double* __restrict__ pair_cls,
    const unsigned* __restrict__ pair_pos,
    double* __restrict__ obj_sum, unsigned* __restrict__ obj_cnt,
    unsigned* __restrict__ ticket,
    float* __restrict__ out)
{
    const int tid = threadIdx.x;
    int idx = blockIdx.x * 256 + tid;
    double term = 0.0; unsigned tc = 0u;
    if (idx < NTOT) {
        const float* o; int li, lbase;
        if (idx < 262144)      { o = o0; li = idx;          lbase = 0; }
        else if (idx < 327680) { o = o1; li = idx - 262144; lbase = 8192; }
        else                   { o = o2; li = idx - 327680; lbase = 10240; }
        float x = o[li];
        unsigned bit = (objbits[lbase + (li >> 5)] >> (li & 31)) & 1u;
        if (bit) { term = (double)(1.2f * softplus_f(-x)); tc = 1u; }
        else     { term = (double)softplus_f(x); }
    }
    for (int off = 32; off > 0; off >>= 1) {
        term += __shfl_down(term, off);
        tc   += __shfl_down(tc, off);
    }
    __shared__ double rterm[4]; __shared__ unsigned rtc[4];
    __shared__ unsigned s_rank;
    int wave = tid >> 6, lane = tid & 63;
    if (lane == 0) { rterm[wave] = term; rtc[wave] = tc; }
    __syncthreads();
    if (tid == 0) {
        obj_sum[blockIdx.x] = rterm[0] + rterm[1] + rterm[2] + rterm[3];
        obj_cnt[blockIdx.x] = rtc[0] + rtc[1] + rtc[2] + rtc[3];
    }
    __threadfence();
    if (tid == 0) s_rank = atomicAdd(ticket, 1u);
    __syncthreads();
    if (s_rank != (unsigned)(NOBJB - 1)) return;
    __threadfence();   // acquire side

    // ---- last block: final reduction ----
    double reg = 0.0, cls = 0.0, obj = 0.0;
    unsigned pc = 0u, oc = 0u;
    for (int i = tid; i < NPAIR; i += 256) {
        reg += pair_reg[i]; cls += pair_cls[i]; pc += pair_pos[i];
    }
    for (int i = tid; i < NOBJB; i += 256) {
        obj += obj_sum[i]; oc += obj_cnt[i];
    }
    for (int off = 32; off > 0; off >>= 1) {
        reg += __shfl_down(reg, off);
        cls += __shfl_down(cls, off);
        obj += __shfl_down(obj, off);
        pc  += __shfl_down(pc, off);
        oc  += __shfl_down(oc, off);
    }
    __shared__ double rr[4], rc[4], ro[4];
    __shared__ unsigned rp[4], rn[4];
    if (lane == 0) { rr[wave] = reg; rc[wave] = cls; ro[wave] = obj; rp[wave] = pc; rn[wave] = oc; }
    __syncthreads();
    if (tid == 0) {
        double sreg = 0, scls = 0, sobj = 0; unsigned spc = 0, soc = 0;
        #pragma unroll
        for (int i = 0; i < 4; ++i) {
            sreg += rr[i]; scls += rc[i]; sobj += ro[i]; spc += rp[i]; soc += rn[i];
        }
        double nc = (double)NTOT - (double)soc;
        double pos_eps = fmax((double)spc, 1.0);
        double den = pos_eps + fmax(nc, 1.0);
        out[0] = (float)(sreg / pos_eps + sobj / den + scls / pos_eps);
    }
}

extern "C" void kernel_launch(void* const* d_in, const int* in_sizes, int n_in,
                              void* d_out, int out_size, void* d_ws, size_t ws_size,
                              hipStream_t stream)
{
    (void)in_sizes; (void)n_in; (void)out_size; (void)ws_size;
    const float* reg0 = (const float*)d_in[0];
    const float* obj0 = (const float*)d_in[1];
    const float* cls0 = (const float*)d_in[2];
    const float* reg1 = (const float*)d_in[3];
    const float* obj1 = (const float*)d_in[4];
    const float* cls1 = (const float*)d_in[5];
    const float* reg2 = (const float*)d_in[6];
    const float* obj2 = (const float*)d_in[7];
    const float* cls2 = (const float*)d_in[8];
    const float* gt   = (const float*)d_in[9];

    // ws layout:
    char* ws = (char*)d_ws;
    unsigned* objbits  = (unsigned*)ws;                  // u32[10752] [0, 43008)
    unsigned* ticket   = (unsigned*)(ws + 43008);        // u32        [43008, 43012)
    double*   pair_reg = (double*)(ws + 43016);          // f64[1536]  [43016, 55304)
    double*   pair_cls = (double*)(ws + 55304);          // f64[1536]  [55304, 67592)
    unsigned* pair_pos = (unsigned*)(ws + 67592);        // u32[1536]  [67592, 73736)
    double*   obj_sum  = (double*)(ws + 73736);          // f64[1344]  [73736, 84488)
    unsigned* obj_cnt  = (unsigned*)(ws + 84488);        // u32[1344]  [84488, 89864)

    zero_kernel<<<43, 256, 0, stream>>>((unsigned*)ws, 10753);  // objbits + ticket
    pair_kernel<<<NPAIR, PBLK, 0, stream>>>(gt, reg0, cls0, reg1, cls1, reg2, cls2,
                                            objbits, pair_reg, pair_cls, pair_pos);
    objfin_kernel<<<NOBJB, 256, 0, stream>>>(obj0, obj1, obj2, objbits,
                                             pair_reg, pair_cls, pair_pos,
                                             obj_sum, obj_cnt, ticket, (float*)d_out);
}

// Round 7
// 139.401 us; speedup vs baseline: 1.6539x; 1.6539x over previous
//
#include <hip/hip_runtime.h>

#define KCAP 96u
#define CAP 6144          // cached pos-cell list capacity
#define PBLK 512          // select_kernel block size
#define NTOT 344064       // 16*(16384+4096+1024)
#define NPAIR 1536

__device__ __forceinline__ float softplus_f(float x) {
    return fmaxf(x, 0.0f) + log1pf(expf(-fabsf(x)));
}

// Exact reproduction of the reference geometry (no fma contraction so we
// match XLA's elementwise fp32 at the selection decision boundaries).
__device__ __forceinline__ void tri_pos_dist(
    float px, float py,
    float ax, float ay, float bx, float by, float cx, float cy,
    bool& pos, float& dist)
{
#pragma clang fp contract(off)
    float d1 = (px - bx) * (ay - by) - (ax - bx) * (py - by);
    float d2 = (px - cx) * (by - cy) - (bx - cx) * (py - cy);
    float d3 = (px - ax) * (cy - ay) - (cx - ax) * (py - ay);
    bool has_neg = (d1 < 0.f) | (d2 < 0.f) | (d3 < 0.f);
    bool has_pos = (d1 > 0.f) | (d2 > 0.f) | (d3 > 0.f);
    bool inside = !(has_neg && has_pos);

    float dAB, dBC, dCA;
    {
        float vx = bx - ax, vy = by - ay, wx = px - ax, wy = py - ay;
        float t = (wx*vx + wy*vy) / (vx*vx + vy*vy + 1e-9f);
        t = fminf(fmaxf(t, 0.0f), 1.0f);
        float dx = px - (ax + t*vx), dy = py - (ay + t*vy);
        dAB = sqrtf(dx*dx + dy*dy + 1e-12f);
    }
    {
        float vx = cx - bx, vy = cy - by, wx = px - bx, wy = py - by;
        float t = (wx*vx + wy*vy) / (vx*vx + vy*vy + 1e-9f);
        t = fminf(fmaxf(t, 0.0f), 1.0f);
        float dx = px - (bx + t*vx), dy = py - (by + t*vy);
        dBC = sqrtf(dx*dx + dy*dy + 1e-12f);
    }
    {
        float vx = ax - cx, vy = ay - cy, wx = px - cx, wy = py - cy;
        float t = (wx*vx + wy*vy) / (vx*vx + vy*vy + 1e-9f);
        t = fminf(fmaxf(t, 0.0f), 1.0f);
        float dx = px - (cx + t*vx), dy = py - (cy + t*vy);
        dCA = sqrtf(dx*dx + dy*dy + 1e-12f);
    }
    dist = fminf(dAB, fminf(dBC, dCA));
    pos = inside || (dist <= 3.0f);
}

// One block (512 threads) per (level, b, g) pair. Selection ONLY: one heavy
// pass over the ETA-expanded bbox (histogram top-11 bits + cache pos cells
// in LDS), exact 32-bit kth refined from the cache via two cheap LDS passes;
// full-bit ties ranked by hw (matches jax.lax.top_k). Overflow (>CAP) does
// one extra heavy re-cache pass of bin<=T cells; double-overflow falls back
// to heavy radix. Emits the <=96 selected hw per pair + count. Also zeroes
// this block's slice of objbits (7 words) for the next kernel.
__global__ __launch_bounds__(PBLK) void select_kernel(
    const float* __restrict__ gt,
    unsigned* __restrict__ objbits,
    unsigned short* __restrict__ sel,
    unsigned* __restrict__ sel_cnt)
{
    const int bid = blockIdx.x;
    const int tid = threadIdx.x;
    const int lane = tid & 63;

    if (tid < 7) objbits[bid * 7 + tid] = 0u;   // fold objbits zeroing in

    const int level = bid >> 9;        // 512 pairs per level
    const int pair = bid & 511;

    int W, shift;
    float stride;
    if (level == 0)      { W = 128; shift = 7; stride = 8.0f;  }
    else if (level == 1) { W = 64;  shift = 6; stride = 16.0f; }
    else                 { W = 32;  shift = 5; stride = 32.0f; }

    const float* gp = gt + pair * 6;
    const float ax = gp[0], ay = gp[1];
    const float bx = gp[2], by = gp[3];
    const float cx = gp[4], cy = gp[5];

    // ---- expanded bbox of candidate cells (conservative, +1 cell margin) ----
    const float inv = 1.0f / stride;   // power of two: exact
    float minx = fminf(ax, fminf(bx, cx)), maxx = fmaxf(ax, fmaxf(bx, cx));
    float miny = fminf(ay, fminf(by, cy)), maxy = fmaxf(ay, fmaxf(by, cy));
    int wlo = max(0,     (int)floorf((minx - 3.0f) * inv - 0.5f) - 1);
    int whi = min(W - 1, (int)ceilf ((maxx + 3.0f) * inv - 0.5f) + 1);
    int hlo = max(0,     (int)floorf((miny - 3.0f) * inv - 0.5f) - 1);
    int hhi = min(W - 1, (int)ceilf ((maxy + 3.0f) * inv - 0.5f) + 1);
    const int ncols = max(0, whi - wlo + 1);
    const int nb = (hhi - hlo + 1 > 0) ? (hhi - hlo + 1) * ncols : 0;
    const int nbR = (nb + PBLK - 1) & ~(PBLK - 1);
    // magic-multiply division by ncols: exact for i < 2^20, ncols < 2^20
    const unsigned long long dmul =
        (ncols > 0) ? ((1ull << 40) / (unsigned)ncols + 1ull) : 0ull;

    __shared__ unsigned hist[2048];
    __shared__ unsigned chunk[256];
    __shared__ unsigned chunk4[64];
    __shared__ unsigned s_bits[CAP];
    __shared__ unsigned short s_hw[CAP];
    __shared__ unsigned s_cnt, s_T, s_k, s_tiecnt, s_sel;
    unsigned* tie_hw = hist;   // alias: hist is dead once ties are collected

    if (tid == 0) { s_cnt = 0u; s_tiecnt = 0u; s_sel = 0u; }
    for (int j = tid; j < 2048; j += PBLK) hist[j] = 0u;
    __syncthreads();

    // two-level kth scan: hist -> chunk(256x8) -> chunk4(64x32); out: s_T, s_k
    auto kth_scan = [&](unsigned kk) {
        __syncthreads();
        if (tid < 256) {
            unsigned s = 0; int base = tid * 8;
            #pragma unroll
            for (int j = 0; j < 8; ++j) s += hist[base + j];
            chunk[tid] = s;
        }
        __syncthreads();
        if (tid < 64) {
            int b4 = tid * 4;
            chunk4[tid] = chunk[b4] + chunk[b4+1] + chunk[b4+2] + chunk[b4+3];
        }
        __syncthreads();
        if (tid == 0) {
            unsigned cum = 0; int t4 = 0;
            while (cum + chunk4[t4] < kk) { cum += chunk4[t4]; ++t4; }
            int t = t4 * 4;
            while (cum + chunk[t] < kk) { cum += chunk[t]; ++t; }
            int bb = t * 8;
            while (cum + hist[bb] < kk) { cum += hist[bb]; ++bb; }
            s_T = (unsigned)bb;
            s_k = kk - cum;
        }
        __syncthreads();
    };

    auto emit = [&](int hw) {
        unsigned slot = atomicAdd(&s_sel, 1u);
        sel[bid * 96 + slot] = (unsigned short)hw;
    };

    // ---- pass A: single heavy pass; histogram top-11 bits + cache pos cells ----
    for (int i = tid; i < nbR; i += PBLK) {
        bool pos = false; unsigned bits = 0u; int hw = 0;
        if (i < nb) {
            int q = (int)(((unsigned long long)(unsigned)i * dmul) >> 40);
            int w = wlo + (i - q * ncols);
            int h = hlo + q;
            hw = (h << shift) | w;
            float px = (w + 0.5f) * stride;
            float py = (h + 0.5f) * stride;
            float dist;
            tri_pos_dist(px, py, ax, ay, bx, by, cx, cy, pos, dist);
            if (pos) { bits = __float_as_uint(dist); atomicAdd(&hist[bits >> 21], 1u); }
        }
        unsigned long long m = __ballot(pos);
        if (m) {
            int leader = __ffsll(m) - 1;
            unsigned base = 0u;
            if (lane == leader) base = atomicAdd(&s_cnt, (unsigned)__popcll(m));
            base = __shfl(base, leader);
            if (pos) {
                unsigned slot = base + (unsigned)__popcll(m & ((1ull << lane) - 1ull));
                if (slot < CAP) { s_bits[slot] = bits; s_hw[slot] = (unsigned short)hw; }
            }
        }
    }
    __syncthreads();

    const unsigned total = s_cnt;
    const bool fullsel = (total <= KCAP);
    unsigned n = min(total, (unsigned)CAP);
    unsigned kth_bits = 0u, tie_need = 0u;
    bool radix_fb = false;

    if (!fullsel) {
        kth_scan(KCAP);                  // T bin of kth + within-bin rank
        const unsigned T = s_T, kk1 = s_k;

        if (total > CAP) {
            // ---- hybrid: heavy pass 2 re-caches only cells with bin <= T ----
            if (tid == 0) s_cnt = 0u;
            __syncthreads();
            for (int i = tid; i < nbR; i += PBLK) {
                bool keep = false; unsigned bits = 0u; int hw = 0;
                if (i < nb) {
                    int q = (int)(((unsigned long long)(unsigned)i * dmul) >> 40);
                    int w = wlo + (i - q * ncols);
                    int h = hlo + q;
                    hw = (h << shift) | w;
                    float px = (w + 0.5f) * stride;
                    float py = (h + 0.5f) * stride;
                    bool pos; float dist;
                    tri_pos_dist(px, py, ax, ay, bx, by, cx, cy, pos, dist);
                    if (pos) {
                        bits = __float_as_uint(dist);
                        keep = ((bits >> 21) <= T);
                    }
                }
                unsigned long long m = __ballot(keep);
                if (m) {
                    int leader = __ffsll(m) - 1;
                    unsigned base = 0u;
                    if (lane == leader) base = atomicAdd(&s_cnt, (unsigned)__popcll(m));
                    base = __shfl(base, leader);
                    if (keep) {
                        unsigned slot = base + (unsigned)__popcll(m & ((1ull << lane) - 1ull));
                        if (slot < CAP) { s_bits[slot] = bits; s_hw[slot] = (unsigned short)hw; }
                    }
                }
            }
            __syncthreads();
            n = s_cnt;
            if (n > CAP) { radix_fb = true; }
        }

        if (!radix_fb) {
            // ---- exact kth via 2 cheap LDS refinement passes over cache ----
            __syncthreads();
            for (int j = tid; j < 2048; j += PBLK) hist[j] = 0u;
            __syncthreads();
            for (unsigned i = tid; i < n; i += PBLK) {
                unsigned bi = s_bits[i];
                if ((bi >> 21) == T) atomicAdd(&hist[(bi >> 10) & 0x7FFu], 1u);
            }
            kth_scan(kk1);
            unsigned prefix = (T << 11) | s_T;   // top 22 bits
            unsigned kk2 = s_k;
            __syncthreads();
            for (int j = tid; j < 2048; j += PBLK) hist[j] = 0u;
            __syncthreads();
            for (unsigned i = tid; i < n; i += PBLK) {
                unsigned bi = s_bits[i];
                if ((bi >> 10) == prefix) atomicAdd(&hist[bi & 0x3FFu], 1u);
            }
            kth_scan(kk2);
            kth_bits = (prefix << 10) | s_T;     // full 32-bit kth pattern
            tie_need = s_k;
        }
    }

    // ---- emit selected hw ----
    if (fullsel) {
        for (unsigned i = tid; i < n; i += PBLK) emit((int)s_hw[i]);
    } else if (!radix_fb) {
        for (unsigned i = tid; i < n; i += PBLK) {
            unsigned bi = s_bits[i];
            if (bi < kth_bits) {
                emit((int)s_hw[i]);
            } else if (bi == kth_bits) {
                unsigned t = atomicAdd(&s_tiecnt, 1u);
                if (t < 2048u) tie_hw[t] = s_hw[i];
            }
        }
        __syncthreads();
        unsigned tn = min(s_tiecnt, 2048u);
        for (unsigned i = tid; i < tn; i += PBLK) {
            unsigned hwv = tie_hw[i], rank = 0;
            for (unsigned j = 0; j < tn; ++j) rank += (tie_hw[j] < hwv) ? 1u : 0u;
            if (rank < tie_need) emit((int)hwv);
        }
    } else {
        // ---- ultra-rare fallback: heavy radix p=1,2 + final heavy pass ----
        unsigned prefix = s_T;   // T from kth_scan(KCAP); s_T/s_k untouched since
        for (int p = 1; p < 3; ++p) {
            unsigned kk = s_k;
            __syncthreads();
            for (int j = tid; j < 2048; j += PBLK) hist[j] = 0u;
            __syncthreads();
            for (int i = tid; i < nb; i += PBLK) {
                int q = (int)(((unsigned long long)(unsigned)i * dmul) >> 40);
                int w = wlo + (i - q * ncols);
                int h = hlo + q;
                float px = (w + 0.5f) * stride;
                float py = (h + 0.5f) * stride;
                bool pos; float dist;
                tri_pos_dist(px, py, ax, ay, bx, by, cx, cy, pos, dist);
                if (!pos) continue;
                unsigned bits = __float_as_uint(dist);
                unsigned bin;
                if (p == 1) { if ((bits >> 21) != prefix) continue; bin = (bits >> 10) & 0x7FFu; }
                else        { if ((bits >> 10) != prefix) continue; bin = bits & 0x3FFu; }
                atomicAdd(&hist[bin], 1u);
            }
            kth_scan(kk);
            prefix = (p == 1) ? ((prefix << 11) | s_T) : ((prefix << 10) | s_T);
        }
        const unsigned kth = prefix, need = s_k;
        for (int i = tid; i < nb; i += PBLK) {
            int q = (int)(((unsigned long long)(unsigned)i * dmul) >> 40);
            int w = wlo + (i - q * ncols);
            int h = hlo + q;
            int hw = (h << shift) | w;
            float px = (w + 0.5f) * stride;
            float py = (h + 0.5f) * stride;
            bool pos; float dist;
            tri_pos_dist(px, py, ax, ay, bx, by, cx, cy, pos, dist);
            if (!pos) continue;
            unsigned bits = __float_as_uint(dist);
            if (bits < kth) {
                emit(hw);
            } else if (bits == kth) {
                unsigned t = atomicAdd(&s_tiecnt, 1u);
                if (t < 2048u) tie_hw[t] = (unsigned)hw;
            }
        }
        __syncthreads();
        unsigned tn = min(s_tiecnt, 2048u);
        for (unsigned i = tid; i < tn; i += PBLK) {
            unsigned hwv = tie_hw[i], rank = 0;
            for (unsigned j = 0; j < tn; ++j) rank += (tie_hw[j] < hwv) ? 1u : 0u;
            if (rank < need) emit((int)hwv);
        }
    }
    __syncthreads();
    if (tid == 0) sel_cnt[bid] = s_sel;
}

// One block (256 threads) per pair. Section 1: one coalesced cell per thread
// of the global softplus(x) sum (obj base term). Section 2: contributions of
// this pair's selected cells; union-dedup via atomicOr return value adds the
// per-cell obj delta (1.2*sp(-x) - sp(x)) exactly once. No fences.
__global__ __launch_bounds__(256) void contrib_kernel(
    const float* __restrict__ gt,
    const float* __restrict__ reg0, const float* __restrict__ cls0, const float* __restrict__ o0,
    const float* __restrict__ reg1, const float* __restrict__ cls1, const float* __restrict__ o1,
    const float* __restrict__ reg2, const float* __restrict__ cls2, const float* __restrict__ o2,
    const unsigned short* __restrict__ sel, const unsigned* __restrict__ sel_cnt,
    unsigned* __restrict__ objbits,
    double* __restrict__ p_reg, double* __restrict__ p_cls,
    double* __restrict__ p_obj, unsigned* __restrict__ p_tc)
{
    const int bid = blockIdx.x;
    const int tid = threadIdx.x;

    double objAcc = 0.0;
    // ---- section 1: global sum of softplus(obj_x) over all cells ----
    {
        int idx = bid * 256 + tid;
        if (idx < NTOT) {
            const float* o; int li;
            if (idx < 262144)      { o = o0; li = idx; }
            else if (idx < 327680) { o = o1; li = idx - 262144; }
            else                   { o = o2; li = idx - 327680; }
            objAcc = (double)softplus_f(o[li]);
        }
    }

    // ---- section 2: this pair's selected-cell contributions ----
    const int level = bid >> 9;
    const int pair = bid & 511;
    const int b = pair >> 5;
    int W, HW, shift, objbase;
    float stride;
    const float* pr; const float* pcl; const float* po;
    if (level == 0)      { W = 128; HW = 16384; shift = 7; stride = 8.0f;  objbase = 0;     pr = reg0; pcl = cls0; po = o0; }
    else if (level == 1) { W = 64;  HW = 4096;  shift = 6; stride = 16.0f; objbase = 8192;  pr = reg1; pcl = cls1; po = o1; }
    else                 { W = 32;  HW = 1024;  shift = 5; stride = 32.0f; objbase = 10240; pr = reg2; pcl = cls2; po = o2; }
    const int wmask = W - 1;
    const float inv = 1.0f / stride;

    const float* gp = gt + pair * 6;
    const float ax = gp[0], ay = gp[1];
    const float bx = gp[2], by = gp[3];
    const float cx = gp[4], cy = gp[5];

    const unsigned cnt = sel_cnt[bid];
    double regAcc = 0.0, clsAcc = 0.0;
    unsigned tcAcc = 0u;

    for (unsigned i = tid; i < cnt; i += 256) {
        int hw = (int)sel[bid * 96 + i];
        int h = hw >> shift, w = hw & wmask;
        float px = (w + 0.5f) * stride;
        float py = (h + 0.5f) * stride;
        const float* base = pr + (size_t)b * 6 * HW + hw;
        float p0x = base[0],          p0y = base[HW];
        float p1x = base[2 * HW],     p1y = base[3 * HW];
        float p2x = base[4 * HW],     p2y = base[5 * HW];
        float g0x = (ax - px) * inv,  g0y = (ay - py) * inv;
        float g1x = (bx - px) * inv,  g1y = (by - py) * inv;
        float g2x = (cx - px) * inv,  g2y = (cy - py) * inv;
        float dx0 = p0x - g0x, dy0 = p0y - g0y;
        float p0t = dx0 * dx0 + dy0 * dy0;
        float e11x = p1x - g1x, e11y = p1y - g1y;
        float e12x = p1x - g2x, e12y = p1y - g2y;
        float e21x = p2x - g1x, e21y = p2y - g1y;
        float e22x = p2x - g2x, e22y = p2y - g2y;
        float d11 = sqrtf(e11x * e11x + e11y * e11y);
        float d12 = sqrtf(e12x * e12x + e12y * e12y);
        float d21 = sqrtf(e21x * e21x + e21y * e21y);
        float d22 = sqrtf(e22x * e22x + e22y * e22y);
        float cd = fminf(d11, d12) + fminf(d21, d22) + fminf(d11, d21) + fminf(d12, d22);
        regAcc += (double)(p0t + cd);
        clsAcc += (double)softplus_f(-pcl[(size_t)b * HW + hw]);

        unsigned bi = (unsigned)(b * HW + hw);
        unsigned bit = 1u << (bi & 31u);
        unsigned old = atomicOr(&objbits[objbase + (bi >> 5)], bit);
        if (!(old & bit)) {           // first pair to claim this cell
            float x = po[(size_t)b * HW + hw];
            float spx = softplus_f(x);
            objAcc += (double)(1.2f * softplus_f(-x)) - (double)spx;
            tcAcc += 1u;
        }
    }

    // ---- block reduce + per-block partial write ----
    for (int off = 32; off > 0; off >>= 1) {
        regAcc += __shfl_down(regAcc, off);
        clsAcc += __shfl_down(clsAcc, off);
        objAcc += __shfl_down(objAcc, off);
        tcAcc  += __shfl_down(tcAcc, off);
    }
    __shared__ double rr[4], rc[4], ro[4];
    __shared__ unsigned rt[4];
    int wave = tid >> 6, lane = tid & 63;
    if (lane == 0) { rr[wave] = regAcc; rc[wave] = clsAcc; ro[wave] = objAcc; rt[wave] = tcAcc; }
    __syncthreads();
    if (tid == 0) {
        p_reg[bid] = rr[0] + rr[1] + rr[2] + rr[3];
        p_cls[bid] = rc[0] + rc[1] + rc[2] + rc[3];
        p_obj[bid] = ro[0] + ro[1] + ro[2] + ro[3];
        p_tc[bid]  = rt[0] + rt[1] + rt[2] + rt[3];
    }
}

__global__ __launch_bounds__(1024) void finalize_kernel(
    const double* __restrict__ p_reg, const double* __restrict__ p_cls,
    const double* __restrict__ p_obj, const unsigned* __restrict__ p_tc,
    const unsigned* __restrict__ sel_cnt,
    float* __restrict__ out)
{
    const int tid = threadIdx.x;
    double reg = 0.0, cls = 0.0, obj = 0.0;
    unsigned pc = 0u, tc = 0u;
    for (int i = tid; i < NPAIR; i += 1024) {
        reg += p_reg[i]; cls += p_cls[i]; obj += p_obj[i];
        tc += p_tc[i]; pc += sel_cnt[i];
    }
    for (int off = 32; off > 0; off >>= 1) {
        reg += __shfl_down(reg, off);
        cls += __shfl_down(cls, off);
        obj += __shfl_down(obj, off);
        pc  += __shfl_down(pc, off);
        tc  += __shfl_down(tc, off);
    }
    __shared__ double rr[16], rc[16], ro[16];
    __shared__ unsigned rp[16], rn[16];
    int wave = tid >> 6, lane = tid & 63;
    if (lane == 0) { rr[wave] = reg; rc[wave] = cls; ro[wave] = obj; rp[wave] = pc; rn[wave] = tc; }
    __syncthreads();
    if (tid == 0) {
        double sreg = 0, scls = 0, sobj = 0; unsigned spc = 0, stc = 0;
        #pragma unroll
        for (int i = 0; i < 16; ++i) {
            sreg += rr[i]; scls += rc[i]; sobj += ro[i]; spc += rp[i]; stc += rn[i];
        }
        double nc = (double)NTOT - (double)stc;
        double pos_eps = fmax((double)spc, 1.0);
        double den = pos_eps + fmax(nc, 1.0);
        out[0] = (float)(sreg / pos_eps + sobj / den + scls / pos_eps);
    }
}

extern "C" void kernel_launch(void* const* d_in, const int* in_sizes, int n_in,
                              void* d_out, int out_size, void* d_ws, size_t ws_size,
                              hipStream_t stream)
{
    (void)in_sizes; (void)n_in; (void)out_size; (void)ws_size;
    const float* reg0 = (const float*)d_in[0];
    const float* obj0 = (const float*)d_in[1];
    const float* cls0 = (const float*)d_in[2];
    const float* reg1 = (const float*)d_in[3];
    const float* obj1 = (const float*)d_in[4];
    const float* cls1 = (const float*)d_in[5];
    const float* reg2 = (const float*)d_in[6];
    const float* obj2 = (const float*)d_in[7];
    const float* cls2 = (const float*)d_in[8];
    const float* gt   = (const float*)d_in[9];

    // ws layout:
    char* ws = (char*)d_ws;
    unsigned*       objbits = (unsigned*)ws;              // u32[10752]    [0,      43008)
    unsigned short* sel     = (unsigned short*)(ws + 43008); // u16[1536*96] [43008, 337920)
    unsigned*       sel_cnt = (unsigned*)(ws + 337920);   // u32[1536]     [337920,344064)
    double*         p_reg   = (double*)(ws + 344064);     // f64[1536]     [344064,356352)
    double*         p_cls   = (double*)(ws + 356352);     // f64[1536]     [356352,368640)
    double*         p_obj   = (double*)(ws + 368640);     // f64[1536]     [368640,380928)
    unsigned*       p_tc    = (unsigned*)(ws + 380928);   // u32[1536]     [380928,387072)

    select_kernel<<<NPAIR, PBLK, 0, stream>>>(gt, objbits, sel, sel_cnt);
    contrib_kernel<<<NPAIR, 256, 0, stream>>>(gt,
                                              reg0, cls0, obj0,
                                              reg1, cls1, obj1,
                                              reg2, cls2, obj2,
                                              sel, sel_cnt, objbits,
                                              p_reg, p_cls, p_obj, p_tc);
    finalize_kernel<<<1, 1024, 0, stream>>>(p_reg, p_cls, p_obj, p_tc, sel_cnt,
                                            (float*)d_out);
}